// Round 9
// baseline (45.455 us; speedup 1.0000x reference)
//
#include <hip/hip_runtime.h>
#include <hip/hip_bf16.h>

// Problem constants: B=1, N=1024, T=2048, E=16384, K=32.
#define TT  2048
#define KK  32
#define NN  1024
#define EE  16384
#define CAP 64   // per-row expert cap (Poisson(16); P(>64) ~ 1e-21)

typedef short short8  __attribute__((ext_vector_type(8)));
typedef short short4v __attribute__((ext_vector_type(4)));
typedef float f32x4   __attribute__((ext_vector_type(4)));

// Pre-converted bf16 copies (device globals: no ws dependence, rewritten each call).
__device__ short g_xbf[NN * TT];   // 4 MB
__device__ short g_kbf[EE * KK];   // 1 MB

__device__ __forceinline__ short f2bf(float f) {
    __hip_bfloat16 h = __float2bfloat16(f);
    return __builtin_bit_cast(short, h);
}

// Async global->LDS DMA, 16 B/lane: LDS dest = uniform base + lane*16 (HW rule).
__device__ __forceinline__ void gload_lds16(const short* g, short* l) {
    __builtin_amdgcn_global_load_lds(
        (const __attribute__((address_space(1))) void*)(const void*)(g),
        (__attribute__((address_space(3))) void*)(void*)(l), 16, 0, 0);
}

// Prep: x fp32 -> bf16 (blocks 0..1023), kern fp32 -> bf16 (blocks 1024..1279).
__global__ __launch_bounds__(256) void prep_kernel(const float* __restrict__ x,
                                                   const float* __restrict__ kern) {
    const int bid = blockIdx.x;
    if (bid < NN) {
        const int i = bid * 256 + threadIdx.x;           // 262144 threads, 8 floats
        const float4* x4 = (const float4*)x;
        const float4 a = x4[2 * i], b = x4[2 * i + 1];
        short8 h;
        h[0]=f2bf(a.x); h[1]=f2bf(a.y); h[2]=f2bf(a.z); h[3]=f2bf(a.w);
        h[4]=f2bf(b.x); h[5]=f2bf(b.y); h[6]=f2bf(b.z); h[7]=f2bf(b.w);
        ((short8*)g_xbf)[i] = h;
    } else {
        const int i = (bid - NN) * 256 + threadIdx.x;    // 65536 threads, 8 floats
        const float4* k4 = (const float4*)kern;
        const float4 a = k4[2 * i], b = k4[2 * i + 1];
        short8 h;
        h[0]=f2bf(a.x); h[1]=f2bf(a.y); h[2]=f2bf(a.z); h[3]=f2bf(a.w);
        h[4]=f2bf(b.x); h[5]=f2bf(b.y); h[6]=f2bf(b.z); h[7]=f2bf(b.w);
        ((short8*)g_kbf)[i] = h;
    }
}

// Main: one block per row n, 4 independent waves own 512-wide t-slices.
// 3-deep async expert pipeline per wave: stage cluster = exactly 3 VMEM ops
// {DMA slice, halo load (masked), tap load} -> manual vmcnt(6/3/0) is exact.
// Verified MFMA math (R2-R7): per 256-output segment s of the slice,
//   A1 b128 at xs[256s+16c+8g], A2 at +16   (xs = [32 halo | 512 slice] bf16)
//   b1 = kt[a][s1..+8), b2 = kt[a][s1+16..+24) with g<2 -> 0 (REQUIRED)
//   kt[a][((a+1)&7)+47-m] = tap[m];  a=c&7, s1=((a+1)&7)+15-c+8g (8-aligned)
//   D: col=c=lane&15, row=4g+qd -> t = 512w + 256s + 64g + 16qd + c
__global__ __launch_bounds__(256, 8) void lti_kernel(
    const float* __restrict__ x,     // [N, T] fp32 (epilogue skip-connection)
    const int*   __restrict__ src,   // [E]
    const int*   __restrict__ dst,   // [E]
    float*       __restrict__ out)   // [N, T]
{
    const int n   = blockIdx.x;
    const int tid = threadIdx.x;
    const int w   = tid >> 6;        // t-slice 0..3
    const int ln  = tid & 63;
    const int c   = ln & 15, g = ln >> 4;
    const int t0  = 512 * w;
    const int hoff = w ? (t0 - 32) : 0;   // halo src (w=0 reads dummy, never commits)

    __shared__ __align__(16) short xs_all[4][3][544];  // per-wave 3 bufs [32 halo|512]
    __shared__ __align__(16) short kt_all[4][8][72];   // per-wave shifted taps table
    __shared__ int bl[CAP];
    __shared__ int bc;

    short (*xsb)[544] = xs_all[w];
    short (*kt)[72]   = kt_all[w];

    short8 z8; z8[0]=0;z8[1]=0;z8[2]=0;z8[3]=0;z8[4]=0;z8[5]=0;z8[6]=0;z8[7]=0;

    if (tid == 0) bc = 0;
    {   // zero taps table (pads persist); wave-0 zeroes halos of all 3 bufs (persist)
        short8* kz = (short8*)&kt[0][0];   // 576 shorts = 72 short8
        kz[ln] = z8;
        if (ln < 8) kz[64 + ln] = z8;
        if (w == 0 && ln < 12) *(short8*)&xs_all[0][ln >> 2][8 * (ln & 3)] = z8;
    }
    __syncthreads();

    // Block-coop dst scan -> expert list for row n.
    const int4* d4 = (const int4*)dst;
    #pragma unroll
    for (int it = 0; it < EE / 1024; ++it) {
        const int i4 = tid + 256 * it;
        const int4 d = d4[i4];
        const int eb = 4 * i4;
        if (d.x == n) { int p = atomicAdd(&bc, 1); if (p < CAP) bl[p] = (src[eb    ] << 14) | (eb    ); }
        if (d.y == n) { int p = atomicAdd(&bc, 1); if (p < CAP) bl[p] = (src[eb + 1] << 14) | (eb + 1); }
        if (d.z == n) { int p = atomicAdd(&bc, 1); if (p < CAP) bl[p] = (src[eb + 2] << 14) | (eb + 2); }
        if (d.w == n) { int p = atomicAdd(&bc, 1); if (p < CAP) bl[p] = (src[eb + 3] << 14) | (eb + 3); }
    }
    __syncthreads();
    int L = bc; if (L > CAP) L = CAP;

    f32x4 acc0 = {0,0,0,0}, acc1 = {0,0,0,0};
    short8  hr0, hr1, hr2;             // halo regs per stage
    short4v tr0, tr1, tr2;             // tap regs per stage

    const int a_ = c & 7;
    const int s1 = ((a_ + 1) & 7) + 15 - c + 8 * g;   // b128-aligned by construction

    // Cluster: EXACTLY 3 VMEM ops (DMA + masked halo load + tap load) — vmcnt math.
    #define ISSUE(S, P)                                                                \
    {                                                                                  \
        const unsigned sv = (unsigned)bl[P];                                           \
        const int e0 = __builtin_amdgcn_readfirstlane((int)(sv & 16383u));             \
        const int s0 = __builtin_amdgcn_readfirstlane((int)(sv >> 14));                \
        const short* rb = g_xbf + (size_t)s0 * TT;                                     \
        gload_lds16(rb + t0 + 8 * ln, &xsb[S][32]);                                    \
        if (ln < 4) hr##S = *(const short8*)(rb + hoff + 8 * ln);                      \
        tr##S = *(const short4v*)(g_kbf + ((size_t)e0 << 5) + 4 * (ln & 7));           \
    }

    #define COMMIT(S)                                                                  \
    {                                                                                  \
        if (w && ln < 4) *(short8*)&xsb[S][8 * ln] = hr##S;                            \
        const int a2 = ln >> 3, pad = (a2 + 1) & 7, mb = 4 * (ln & 7);                 \
        kt[a2][pad + 47 - mb] = tr##S[0];                                              \
        kt[a2][pad + 46 - mb] = tr##S[1];                                              \
        kt[a2][pad + 45 - mb] = tr##S[2];                                              \
        kt[a2][pad + 44 - mb] = tr##S[3];                                              \
    }

    #define COMPUTE(S)                                                                 \
    {                                                                                  \
        const short8 b1 = *(const short8*)&kt[a_][s1];                                 \
        short8 b2 = *(const short8*)&kt[a_][s1 + 16];                                  \
        if (g < 2) b2 = z8;   /* k<16 zeroing is REQUIRED */                           \
        {                                                                              \
            const short8 a1  = *(const short8*)&xsb[S][16 * c + 8 * g];                \
            const short8 a2v = *(const short8*)&xsb[S][16 * c + 8 * g + 16];           \
            acc0 = __builtin_amdgcn_mfma_f32_16x16x32_bf16(a1,  b1, acc0, 0, 0, 0);    \
            acc0 = __builtin_amdgcn_mfma_f32_16x16x32_bf16(a2v, b2, acc0, 0, 0, 0);    \
        }                                                                              \
        {                                                                              \
            const short8 a1  = *(const short8*)&xsb[S][256 + 16 * c + 8 * g];          \
            const short8 a2v = *(const short8*)&xsb[S][256 + 16 * c + 8 * g + 16];     \
            acc1 = __builtin_amdgcn_mfma_f32_16x16x32_bf16(a1,  b1, acc1, 0, 0, 0);    \
            acc1 = __builtin_amdgcn_mfma_f32_16x16x32_bf16(a2v, b2, acc1, 0, 0, 0);    \
        }                                                                              \
    }

    // Per body: wait so stage I's cluster is retired, then commit+compute it.
    #define BODY(SC, SN, I)                                                            \
    if ((I) < L) {                                                                     \
        __builtin_amdgcn_sched_barrier(0);                                             \
        if ((I) + 2 < L) ISSUE(SN, (I) + 2);                                           \
        const int rem = L - (I);                                                       \
        if (rem >= 3)      { asm volatile("s_waitcnt vmcnt(6)" ::: "memory"); }        \
        else if (rem == 2) { asm volatile("s_waitcnt vmcnt(3)" ::: "memory"); }        \
        else               { asm volatile("s_waitcnt vmcnt(0)" ::: "memory"); }        \
        __builtin_amdgcn_sched_barrier(0);                                             \
        COMMIT(SC);                                                                    \
        COMPUTE(SC);                                                                   \
    }

    if (L > 0) ISSUE(0, 0);
    if (L > 1) ISSUE(1, 1);
    for (int i = 0; i < L; i += 3) {
        BODY(0, 2, i);
        BODY(1, 0, i + 1);
        BODY(2, 1, i + 2);
    }

    // Epilogue: wave owns out[n, t0..t0+512) exclusively -> plain stores (always
    // executed: full overwrite of poisoned d_out; acc==0 when L==0).
    const float* xr  = x   + (size_t)n * TT + t0;
    float*       orw = out + (size_t)n * TT + t0;
    #pragma unroll
    for (int qd = 0; qd < 4; ++qd) {
        const int ta = 64 * g + 16 * qd + c;
        orw[ta]       = xr[ta]       + acc0[qd];
        orw[256 + ta] = xr[256 + ta] + acc1[qd];
    }
    #undef ISSUE
    #undef COMMIT
    #undef COMPUTE
    #undef BODY
}

extern "C" void kernel_launch(void* const* d_in, const int* in_sizes, int n_in,
                              void* d_out, int out_size, void* d_ws, size_t ws_size,
                              hipStream_t stream) {
    const float* x    = (const float*)d_in[0];
    const float* kern = (const float*)d_in[1];
    const int*   src  = (const int*)d_in[2];
    const int*   dst  = (const int*)d_in[3];
    float*       out  = (float*)d_out;

    prep_kernel<<<dim3(NN + EE * KK / 8 / 256), dim3(256), 0, stream>>>(x, kern);
    lti_kernel<<<dim3(NN), dim3(256), 0, stream>>>(x, src, dst, out);
}

// Round 10
// 42.230 us; speedup vs baseline: 1.0764x; 1.0764x over previous
//
#include <hip/hip_runtime.h>
#include <hip/hip_bf16.h>

// Problem constants: B=1, N=1024, T=2048, E=16384, K=32.
#define TT  2048
#define KK  32
#define NN  1024
#define EE  16384
#define CAP 64   // per-row expert cap (Poisson(16); P(>64) ~ 1e-21)

typedef short short8  __attribute__((ext_vector_type(8)));
typedef short short4v __attribute__((ext_vector_type(4)));
typedef float f32x4   __attribute__((ext_vector_type(4)));

// Pre-converted bf16 copies (device globals, rewritten every call).
__device__ short g_xbf[NN * TT];   // 4 MB
__device__ short g_kbf[EE * KK];   // 1 MB

__device__ __forceinline__ short f2bf(float f) {
    __hip_bfloat16 h = __float2bfloat16(f);
    return __builtin_bit_cast(short, h);
}

// Async global->LDS DMA, 16 B/lane of the ACTIVE lanes (dest = base + lane*16).
__device__ __forceinline__ void gload_lds16(const short* g, short* l) {
    __builtin_amdgcn_global_load_lds(
        (const __attribute__((address_space(1))) void*)(const void*)(g),
        (__attribute__((address_space(3))) void*)(void*)(l), 16, 0, 0);
}

// Prep: x fp32 -> bf16 (blocks 0..1023), kern fp32 -> bf16 (blocks 1024..1279).
__global__ __launch_bounds__(256) void prep_kernel(const float* __restrict__ x,
                                                   const float* __restrict__ kern) {
    const int bid = blockIdx.x;
    if (bid < NN) {
        const int i = bid * 256 + threadIdx.x;
        const float4* x4 = (const float4*)x;
        const float4 a = x4[2 * i], b = x4[2 * i + 1];
        short8 h;
        h[0]=f2bf(a.x); h[1]=f2bf(a.y); h[2]=f2bf(a.z); h[3]=f2bf(a.w);
        h[4]=f2bf(b.x); h[5]=f2bf(b.y); h[6]=f2bf(b.z); h[7]=f2bf(b.w);
        ((short8*)g_xbf)[i] = h;
    } else {
        const int i = (bid - NN) * 256 + threadIdx.x;
        const float4* k4 = (const float4*)kern;
        const float4 a = k4[2 * i], b = k4[2 * i + 1];
        short8 h;
        h[0]=f2bf(a.x); h[1]=f2bf(a.y); h[2]=f2bf(a.z); h[3]=f2bf(a.w);
        h[4]=f2bf(b.x); h[5]=f2bf(b.y); h[6]=f2bf(b.z); h[7]=f2bf(b.w);
        ((short8*)g_kbf)[i] = h;
    }
}

// Main: one block per row n, 512 threads = 8 waves. Wave v = (slice w=v&3, parity
// q=v>>2). Wave handles experts p = q, q+2, ... over its 512-wide t-slice with a
// 3-deep async DMA pipeline. Cluster = EXACTLY 3 VMEM ops {slice DMA, halo DMA
// (4 lanes; dummy dest when w==0), tap load} -> vmcnt(6/3/0) math is exact.
// Parity partials combine through the parity-1 wave's own (finished) xs buffers.
// Verified MFMA math (R2-R8): per 256-output segment s of the slice,
//   A1 b128 at xs[256s+16c+8g], A2 at +16   (xs = [32 halo | 512 slice] bf16)
//   b1 = kt[a][s1..+8), b2 = kt[a][s1+16..+24) with g<2 -> 0 (REQUIRED)
//   kt[a][((a+1)&7)+47-m] = tap[m];  a=c&7, s1=((a+1)&7)+15-c+8g (8-aligned)
//   D: col=c=lane&15, row=4g+qd -> t = 512w + 256s + 64g + 16qd + c
__global__ __launch_bounds__(512, 8) void lti_kernel(
    const float* __restrict__ x,     // [N, T] fp32 (epilogue skip-connection)
    const int*   __restrict__ src,   // [E]
    const int*   __restrict__ dst,   // [E]
    float*       __restrict__ out)   // [N, T]
{
    const int n   = blockIdx.x;
    const int tid = threadIdx.x;
    const int v   = tid >> 6;        // wave 0..7
    const int w   = v & 3;           // t-slice
    const int q   = v >> 2;          // expert parity
    const int ln  = tid & 63;
    const int c   = ln & 15, g = ln >> 4;
    const int t0  = 512 * w;

    __shared__ __align__(16) short xs_all[8][3][544];  // per-wave 3 bufs [32 halo|512]
    __shared__ __align__(16) short kt_all[8][8][72];   // per-wave shifted taps table
    __shared__ __align__(16) short dummy[32];          // w==0 halo-DMA sink (64 B)
    __shared__ int bl[CAP];
    __shared__ int bc;

    short (*xsb)[544] = xs_all[v];
    short (*kt)[72]   = kt_all[v];

    short8 z8; z8[0]=0;z8[1]=0;z8[2]=0;z8[3]=0;z8[4]=0;z8[5]=0;z8[6]=0;z8[7]=0;

    if (tid == 0) bc = 0;
    {   // zero own taps table (pads persist); w==0 waves zero own 3 halos (persist)
        short8* kz = (short8*)&kt[0][0];   // 576 shorts = 72 short8
        kz[ln] = z8;
        if (ln < 8) kz[64 + ln] = z8;
        if (w == 0 && ln < 12) *(short8*)&xsb[ln >> 2][8 * (ln & 3)] = z8;
    }
    __syncthreads();

    // Block-coop dst scan -> expert list for row n (8 int4 iters, all in flight).
    const int4* d4 = (const int4*)dst;
    #pragma unroll
    for (int it = 0; it < EE / 2048; ++it) {
        const int i4 = tid + 512 * it;
        const int4 d = d4[i4];
        const int eb = 4 * i4;
        if (d.x == n) { int p = atomicAdd(&bc, 1); if (p < CAP) bl[p] = (src[eb    ] << 14) | (eb    ); }
        if (d.y == n) { int p = atomicAdd(&bc, 1); if (p < CAP) bl[p] = (src[eb + 1] << 14) | (eb + 1); }
        if (d.z == n) { int p = atomicAdd(&bc, 1); if (p < CAP) bl[p] = (src[eb + 2] << 14) | (eb + 2); }
        if (d.w == n) { int p = atomicAdd(&bc, 1); if (p < CAP) bl[p] = (src[eb + 3] << 14) | (eb + 3); }
    }
    __syncthreads();
    int L = bc; if (L > CAP) L = CAP;
    const int M = (L - q + 1) >> 1;          // this wave's expert count
    #define IDX(I) (q + 2 * (I))

    f32x4 acc0 = {0,0,0,0}, acc1 = {0,0,0,0};
    short4v tr0, tr1, tr2;                   // tap regs per stage

    short* hdst = w ? (short*)nullptr : dummy;   // fixed below per stage

    const int a_ = c & 7;
    const int s1 = ((a_ + 1) & 7) + 15 - c + 8 * g;   // b128-aligned by construction

    // Cluster: EXACTLY 3 VMEM ops. Halo DMA: 4 active lanes write 64 B to
    // xsb[S][0..31] (w>0) or dummy (w==0, keeps per-wave vmcnt math uniform).
    #define ISSUE(S, P)                                                                \
    {                                                                                  \
        const unsigned sv = (unsigned)bl[P];                                           \
        const int e0 = __builtin_amdgcn_readfirstlane((int)(sv & 16383u));             \
        const int s0 = __builtin_amdgcn_readfirstlane((int)(sv >> 14));                \
        const short* rb = g_xbf + (size_t)s0 * TT;                                     \
        gload_lds16(rb + t0 + 8 * ln, &xsb[S][32]);                                    \
        if (ln < 4)                                                                    \
            gload_lds16(rb + (w ? t0 - 32 : 0) + 8 * ln, w ? &xsb[S][0] : dummy);      \
        tr##S = *(const short4v*)(g_kbf + ((size_t)e0 << 5) + 4 * (ln & 7));           \
    }

    #define COMMIT(S)                                                                  \
    {                                                                                  \
        const int a2 = ln >> 3, pad = (a2 + 1) & 7, mb = 4 * (ln & 7);                 \
        kt[a2][pad + 47 - mb] = tr##S[0];                                              \
        kt[a2][pad + 46 - mb] = tr##S[1];                                              \
        kt[a2][pad + 45 - mb] = tr##S[2];                                              \
        kt[a2][pad + 44 - mb] = tr##S[3];                                              \
    }

    #define COMPUTE(S)                                                                 \
    {                                                                                  \
        const short8 b1 = *(const short8*)&kt[a_][s1];                                 \
        short8 b2 = *(const short8*)&kt[a_][s1 + 16];                                  \
        if (g < 2) b2 = z8;   /* k<16 zeroing is REQUIRED */                           \
        {                                                                              \
            const short8 a1  = *(const short8*)&xsb[S][16 * c + 8 * g];                \
            const short8 a2v = *(const short8*)&xsb[S][16 * c + 8 * g + 16];           \
            acc0 = __builtin_amdgcn_mfma_f32_16x16x32_bf16(a1,  b1, acc0, 0, 0, 0);    \
            acc0 = __builtin_amdgcn_mfma_f32_16x16x32_bf16(a2v, b2, acc0, 0, 0, 0);    \
        }                                                                              \
        {                                                                              \
            const short8 a1  = *(const short8*)&xsb[S][256 + 16 * c + 8 * g];          \
            const short8 a2v = *(const short8*)&xsb[S][256 + 16 * c + 8 * g + 16];     \
            acc1 = __builtin_amdgcn_mfma_f32_16x16x32_bf16(a1,  b1, acc1, 0, 0, 0);    \
            acc1 = __builtin_amdgcn_mfma_f32_16x16x32_bf16(a2v, b2, acc1, 0, 0, 0);    \
        }                                                                              \
    }

    #define BODY(SC, SN, I)                                                            \
    if ((I) < M) {                                                                     \
        __builtin_amdgcn_sched_barrier(0);                                             \
        if ((I) + 2 < M) ISSUE(SN, IDX((I) + 2));                                      \
        const int rem = M - (I);                                                       \
        if (rem >= 3)      { asm volatile("s_waitcnt vmcnt(6)" ::: "memory"); }        \
        else if (rem == 2) { asm volatile("s_waitcnt vmcnt(3)" ::: "memory"); }        \
        else               { asm volatile("s_waitcnt vmcnt(0)" ::: "memory"); }        \
        __builtin_amdgcn_sched_barrier(0);                                             \
        COMMIT(SC);                                                                    \
        COMPUTE(SC);                                                                   \
    }

    if (M > 0) ISSUE(0, IDX(0));
    if (M > 1) ISSUE(1, IDX(1));
    for (int i = 0; i < M; i += 3) {
        BODY(0, 2, i);
        BODY(1, 0, i + 1);
        BODY(2, 1, i + 2);
    }

    // Parity combine: q==1 wave publishes partials into its OWN (finished) xs
    // buffers; barrier; q==0 wave of the same slice combines + stores.
    if (q == 1) {
        float* rd = (float*)&xs_all[v][0][0];   // 3264 B >= 2048 B
        #pragma unroll
        for (int qd = 0; qd < 4; ++qd) {
            const int ta = 64 * g + 16 * qd + c;
            rd[ta]       = acc0[qd];
            rd[256 + ta] = acc1[qd];
        }
    }
    __syncthreads();
    if (q == 0) {
        const float* rd  = (const float*)&xs_all[v + 4][0][0];
        const float* xr  = x   + (size_t)n * TT + t0;
        float*       orw = out + (size_t)n * TT + t0;
        #pragma unroll
        for (int qd = 0; qd < 4; ++qd) {
            const int ta = 64 * g + 16 * qd + c;
            orw[ta]       = xr[ta]       + acc0[qd] + rd[ta];
            orw[256 + ta] = xr[256 + ta] + acc1[qd] + rd[256 + ta];
        }
    }
    #undef IDX
    #undef ISSUE
    #undef COMMIT
    #undef COMPUTE
    #undef BODY
}

extern "C" void kernel_launch(void* const* d_in, const int* in_sizes, int n_in,
                              void* d_out, int out_size, void* d_ws, size_t ws_size,
                              hipStream_t stream) {
    const float* x    = (const float*)d_in[0];
    const float* kern = (const float*)d_in[1];
    const int*   src  = (const int*)d_in[2];
    const int*   dst  = (const int*)d_in[3];
    float*       out  = (float*)d_out;

    prep_kernel<<<dim3(NN + EE * KK / 8 / 256), dim3(256), 0, stream>>>(x, kern);
    lti_kernel<<<dim3(NN), dim3(512), 0, stream>>>(x, src, dst, out);
}

// Round 11
// 42.155 us; speedup vs baseline: 1.0783x; 1.0018x over previous
//
#include <hip/hip_runtime.h>
#include <hip/hip_bf16.h>

// Problem constants: B=1, N=1024, T=2048, E=16384, K=32.
#define TT  2048
#define KK  32
#define NN  1024
#define EE  16384
#define CAP 64   // per-row expert cap (Poisson(16); P(>64) ~ 1e-21)

typedef short short8  __attribute__((ext_vector_type(8)));
typedef short short4v __attribute__((ext_vector_type(4)));
typedef float f32x4   __attribute__((ext_vector_type(4)));

// Pre-converted bf16 copies (device globals, rewritten every call).
__device__ short g_xbf[NN * TT];   // 4 MB
__device__ short g_kbf[EE * KK];   // 1 MB

__device__ __forceinline__ short f2bf(float f) {
    __hip_bfloat16 h = __float2bfloat16(f);
    return __builtin_bit_cast(short, h);
}

// Async global->LDS DMA, 16 B per ACTIVE lane (dest = uniform base + lane*16).
__device__ __forceinline__ void gload_lds16(const short* g, short* l) {
    __builtin_amdgcn_global_load_lds(
        (const __attribute__((address_space(1))) void*)(const void*)(g),
        (__attribute__((address_space(3))) void*)(void*)(l), 16, 0, 0);
}

// Kernel A: x->bf16 (blocks 0..1023), kern->bf16 (1024..1279), zero cnt (1280).
__global__ __launch_bounds__(256) void cvt_kernel(const float* __restrict__ x,
                                                  const float* __restrict__ kern,
                                                  int* __restrict__ cnt) {
    const int bid = blockIdx.x;
    if (bid < NN) {
        const int i = bid * 256 + threadIdx.x;
        const float4* x4 = (const float4*)x;
        const float4 a = x4[2 * i], b = x4[2 * i + 1];
        short8 h;
        h[0]=f2bf(a.x); h[1]=f2bf(a.y); h[2]=f2bf(a.z); h[3]=f2bf(a.w);
        h[4]=f2bf(b.x); h[5]=f2bf(b.y); h[6]=f2bf(b.z); h[7]=f2bf(b.w);
        ((short8*)g_xbf)[i] = h;
    } else if (bid < NN + 256) {
        const int i = (bid - NN) * 256 + threadIdx.x;
        const float4* k4 = (const float4*)kern;
        const float4 a = k4[2 * i], b = k4[2 * i + 1];
        short8 h;
        h[0]=f2bf(a.x); h[1]=f2bf(a.y); h[2]=f2bf(a.z); h[3]=f2bf(a.w);
        h[4]=f2bf(b.x); h[5]=f2bf(b.y); h[6]=f2bf(b.z); h[7]=f2bf(b.w);
        ((short8*)g_kbf)[i] = h;
    } else {
        int4* c4 = (int4*)cnt;
        c4[threadIdx.x] = make_int4(0, 0, 0, 0);   // 256 threads x 16B = 4 KB
    }
}

// Kernel B: routing CSR. slots[d*CAP+p] packs (src<<14)|e.
__global__ __launch_bounds__(256) void csr_kernel(const int* __restrict__ src,
                                                  const int* __restrict__ dst,
                                                  int* __restrict__ cnt,
                                                  unsigned* __restrict__ slots) {
    const int e = blockIdx.x * 256 + threadIdx.x;   // 16384 threads
    const int d = dst[e];
    const int p = atomicAdd(&cnt[d], 1);
    if (p < CAP) slots[(size_t)d * CAP + p] = ((unsigned)src[e] << 14) | (unsigned)e;
}

// Main: grid 4096 in W-MAJOR order (bid = w*1024 + n) so all resident blocks
// share one 512-wide t-slice -> gather working set = 1 MB column of g_xbf
// (+1 MB taps) -> fits every XCD's 4 MB L2 -> gathers L2-hit.
// Block = 256 thr = 4 waves by expert parity q (experts q, q+4, ...), each with
// a 3-deep async DMA pipeline; cluster = EXACTLY 3 VMEM {slice DMA, halo DMA
// (4 lanes; dummy when w==0), tap load} -> vmcnt(6/3/0) math exact.
// Verified MFMA math (R2-R9): per 256-output segment s of the slice,
//   A1 b128 at xs[256s+16c+8g], A2 at +16   (xs = [32 halo | 512 slice] bf16)
//   b1 = kt[a][s1..+8), b2 = kt[a][s1+16..+24) with g<2 -> 0 (REQUIRED)
//   kt[a][((a+1)&7)+47-m] = tap[m];  a=c&7, s1=((a+1)&7)+15-c+8g (8-aligned)
//   D: col=c=lane&15, row=4g+qd -> t = 512w + 256s + 64g + 16qd + c
__global__ __launch_bounds__(256, 6) void lti_kernel(
    const float*    __restrict__ x,      // [N, T] fp32 (epilogue skip-connection)
    const int*      __restrict__ cnt,    // [N]
    const unsigned* __restrict__ slots,  // [N, CAP]
    float*          __restrict__ out)    // [N, T]
{
    const int bid = blockIdx.x;
    const int w   = bid >> 10;       // t-slice phase 0..3 (w-major dispatch order)
    const int n   = bid & 1023;      // row
    const int tid = threadIdx.x;
    const int q   = tid >> 6;        // wave = expert parity 0..3
    const int ln  = tid & 63;
    const int c   = ln & 15, g = ln >> 4;
    const int t0  = 512 * w;

    __shared__ __align__(16) short xs_all[4][3][544];  // per-wave 3 bufs [32 halo|512]
    __shared__ __align__(16) short kt_all[4][8][72];   // per-wave shifted taps table
    __shared__ __align__(16) float red[4][512];        // per-wave partials
    __shared__ __align__(16) short dummy[32];          // w==0 halo-DMA sink
    __shared__ unsigned bl[CAP];

    short (*xsb)[544] = xs_all[q];
    short (*kt)[72]   = kt_all[q];

    short8 z8; z8[0]=0;z8[1]=0;z8[2]=0;z8[3]=0;z8[4]=0;z8[5]=0;z8[6]=0;z8[7]=0;

    {   // per-wave init: zero taps table (pads persist); w==0: zero own 3 halos
        short8* kz = (short8*)&kt[0][0];   // 576 shorts = 72 short8
        kz[ln] = z8;
        if (ln < 8) kz[64 + ln] = z8;
        if (w == 0 && ln < 12) *(short8*)&xsb[ln >> 2][8 * (ln & 3)] = z8;
    }
    // Cache this row's slot list (coalesced; entries >= L never read).
    if (tid < CAP) bl[tid] = slots[(size_t)n * CAP + tid];
    int L = cnt[n]; if (L > CAP) L = CAP;
    __syncthreads();

    const int M = (L - q + 3) >> 2;          // this wave's expert count
    #define IDX(I) (q + 4 * (I))

    f32x4 acc0 = {0,0,0,0}, acc1 = {0,0,0,0};
    short4v tr0, tr1, tr2;                   // tap regs per stage

    const int a_ = c & 7;
    const int s1 = ((a_ + 1) & 7) + 15 - c + 8 * g;   // b128-aligned by construction

    #define ISSUE(S, P)                                                                \
    {                                                                                  \
        const unsigned sv = bl[P];                                                     \
        const int e0 = __builtin_amdgcn_readfirstlane((int)(sv & 16383u));             \
        const int s0 = __builtin_amdgcn_readfirstlane((int)(sv >> 14));                \
        const short* rb = g_xbf + (size_t)s0 * TT;                                     \
        gload_lds16(rb + t0 + 8 * ln, &xsb[S][32]);                                    \
        if (ln < 4)                                                                    \
            gload_lds16(rb + (w ? t0 - 32 : 0) + 8 * ln, w ? &xsb[S][0] : dummy);      \
        tr##S = *(const short4v*)(g_kbf + ((size_t)e0 << 5) + 4 * (ln & 7));           \
    }

    #define COMMIT(S)                                                                  \
    {                                                                                  \
        const int a2 = ln >> 3, pad = (a2 + 1) & 7, mb = 4 * (ln & 7);                 \
        kt[a2][pad + 47 - mb] = tr##S[0];                                              \
        kt[a2][pad + 46 - mb] = tr##S[1];                                              \
        kt[a2][pad + 45 - mb] = tr##S[2];                                              \
        kt[a2][pad + 44 - mb] = tr##S[3];                                              \
    }

    #define COMPUTE(S)                                                                 \
    {                                                                                  \
        const short8 b1 = *(const short8*)&kt[a_][s1];                                 \
        short8 b2 = *(const short8*)&kt[a_][s1 + 16];                                  \
        if (g < 2) b2 = z8;   /* k<16 zeroing is REQUIRED */                           \
        {                                                                              \
            const short8 a1  = *(const short8*)&xsb[S][16 * c + 8 * g];                \
            const short8 a2v = *(const short8*)&xsb[S][16 * c + 8 * g + 16];           \
            acc0 = __builtin_amdgcn_mfma_f32_16x16x32_bf16(a1,  b1, acc0, 0, 0, 0);    \
            acc0 = __builtin_amdgcn_mfma_f32_16x16x32_bf16(a2v, b2, acc0, 0, 0, 0);    \
        }                                                                              \
        {                                                                              \
            const short8 a1  = *(const short8*)&xsb[S][256 + 16 * c + 8 * g];          \
            const short8 a2v = *(const short8*)&xsb[S][256 + 16 * c + 8 * g + 16];     \
            acc1 = __builtin_amdgcn_mfma_f32_16x16x32_bf16(a1,  b1, acc1, 0, 0, 0);    \
            acc1 = __builtin_amdgcn_mfma_f32_16x16x32_bf16(a2v, b2, acc1, 0, 0, 0);    \
        }                                                                              \
    }

    #define BODY(SC, SN, I)                                                            \
    if ((I) < M) {                                                                     \
        __builtin_amdgcn_sched_barrier(0);                                             \
        if ((I) + 2 < M) ISSUE(SN, IDX((I) + 2));                                      \
        const int rem = M - (I);                                                       \
        if (rem >= 3)      { asm volatile("s_waitcnt vmcnt(6)" ::: "memory"); }        \
        else if (rem == 2) { asm volatile("s_waitcnt vmcnt(3)" ::: "memory"); }        \
        else               { asm volatile("s_waitcnt vmcnt(0)" ::: "memory"); }        \
        __builtin_amdgcn_sched_barrier(0);                                             \
        COMMIT(SC);                                                                    \
        COMPUTE(SC);                                                                   \
    }

    if (M > 0) {
        ISSUE(0, IDX(0));
        if (M > 1) ISSUE(1, IDX(1));
        for (int i = 0; i < M; i += 3) {
            BODY(0, 2, i);
            BODY(1, 0, i + 1);
            BODY(2, 1, i + 2);
        }
    }

    // Publish partials (always: zeros when M==0) and block-reduce 4 -> 1.
    {
        float* rd = &red[q][0];
        #pragma unroll
        for (int qd = 0; qd < 4; ++qd) {
            const int ta = 64 * g + 16 * qd + c;
            rd[ta]       = acc0[qd];
            rd[256 + ta] = acc1[qd];
        }
    }
    __syncthreads();
    {   // 256 threads x 2 outputs, coalesced; full overwrite of poisoned d_out.
        const int u = 2 * tid;
        const float2 r0 = *(const float2*)&red[0][u];
        const float2 r1 = *(const float2*)&red[1][u];
        const float2 r2 = *(const float2*)&red[2][u];
        const float2 r3 = *(const float2*)&red[3][u];
        const float2 xv = *(const float2*)(x + (size_t)n * TT + t0 + u);
        float2 o;
        o.x = xv.x + r0.x + r1.x + r2.x + r3.x;
        o.y = xv.y + r0.y + r1.y + r2.y + r3.y;
        *(float2*)(out + (size_t)n * TT + t0 + u) = o;
    }
    #undef IDX
    #undef ISSUE
    #undef COMMIT
    #undef COMPUTE
    #undef BODY
}

extern "C" void kernel_launch(void* const* d_in, const int* in_sizes, int n_in,
                              void* d_out, int out_size, void* d_ws, size_t ws_size,
                              hipStream_t stream) {
    const float* x    = (const float*)d_in[0];
    const float* kern = (const float*)d_in[1];
    const int*   src  = (const int*)d_in[2];
    const int*   dst  = (const int*)d_in[3];
    float*       out  = (float*)d_out;

    int*      cnt   = (int*)d_ws;                       // 4 KB
    unsigned* slots = (unsigned*)((char*)d_ws + 4096);  // 256 KB

    cvt_kernel<<<dim3(NN + 256 + 1), dim3(256), 0, stream>>>(x, kern, cnt);
    csr_kernel<<<dim3(EE / 256), dim3(256), 0, stream>>>(src, dst, cnt, slots);
    lti_kernel<<<dim3(4 * NN), dim3(256), 0, stream>>>(x, cnt, slots, out);
}

// Round 12
// 38.301 us; speedup vs baseline: 1.1868x; 1.1006x over previous
//
#include <hip/hip_runtime.h>
#include <hip/hip_bf16.h>

// Problem constants: B=1, N=1024, T=2048, E=16384, K=32.
#define TT  2048
#define KK  32
#define NN  1024
#define EE  16384
#define CAP 64     // per-row expert cap (Poisson(16); P(>64) ~ 1e-21)
#define RS  2080   // padded bf16 row stride: [32 causal zeros | 2048 row]

typedef short short8  __attribute__((ext_vector_type(8)));
typedef short short4v __attribute__((ext_vector_type(4)));
typedef float f32x4   __attribute__((ext_vector_type(4)));

// bf16 copies (device globals, rewritten every call).
// g_xbf rows are left-padded with 32 zeros -> halo/causality is branchless.
__device__ short g_xbf[NN * RS];   // 4.26 MB  (per-XCD-L2 resident)
__device__ short g_kbf[EE * KK];   // 1 MB

__device__ __forceinline__ short f2bf(float f) {
    __hip_bfloat16 h = __float2bfloat16(f);
    return __builtin_bit_cast(short, h);
}

// Prep A: blocks 0..1023: x row -> padded bf16 row; block 1024: zero cnt;
// blocks 1025..1280: kern -> bf16.
__global__ __launch_bounds__(256) void cvt_kernel(const float* __restrict__ x,
                                                  const float* __restrict__ kern,
                                                  int* __restrict__ cnt) {
    const int bid = blockIdx.x, tid = threadIdx.x;
    if (bid < NN) {
        const float4* xr = (const float4*)(x + (size_t)bid * TT);
        const float4 u = xr[2 * tid], v = xr[2 * tid + 1];
        short8 h;
        h[0]=f2bf(u.x); h[1]=f2bf(u.y); h[2]=f2bf(u.z); h[3]=f2bf(u.w);
        h[4]=f2bf(v.x); h[5]=f2bf(v.y); h[6]=f2bf(v.z); h[7]=f2bf(v.w);
        *(short8*)&g_xbf[(size_t)bid * RS + 32 + 8 * tid] = h;
        if (tid < 4) {
            short8 z; z[0]=0;z[1]=0;z[2]=0;z[3]=0;z[4]=0;z[5]=0;z[6]=0;z[7]=0;
            *(short8*)&g_xbf[(size_t)bid * RS + 8 * tid] = z;   // causal halo
        }
    } else if (bid == NN) {
        ((int4*)cnt)[tid] = make_int4(0, 0, 0, 0);              // 4 KB
    } else {
        const int i = (bid - NN - 1) * 256 + tid;               // 65536 thr, 8 ea
        const float4* k4 = (const float4*)kern;
        const float4 u = k4[2 * i], v = k4[2 * i + 1];
        short8 h;
        h[0]=f2bf(u.x); h[1]=f2bf(u.y); h[2]=f2bf(u.z); h[3]=f2bf(u.w);
        h[4]=f2bf(v.x); h[5]=f2bf(v.y); h[6]=f2bf(v.z); h[7]=f2bf(v.w);
        ((short8*)g_kbf)[i] = h;
    }
}

// Prep B: routing CSR. slots[d*CAP+p] packs (src<<14)|e.
__global__ __launch_bounds__(256) void csr_kernel(const int* __restrict__ src,
                                                  const int* __restrict__ dst,
                                                  int* __restrict__ cnt,
                                                  unsigned* __restrict__ slots) {
    const int e = blockIdx.x * 256 + threadIdx.x;   // 16384 threads
    const int d = dst[e];
    const int p = atomicAdd(&cnt[d], 1);
    if (p < CAP) slots[(size_t)d * CAP + p] = ((unsigned)src[e] << 14) | (unsigned)e;
}

// Main: grid 1024 (one block per row), 256 thr = 4 waves; wave w owns the
// 512-wide t-quarter [512w, 512w+512) and processes ALL experts of the row
// (deep ~16-visit loop). NO x-staging: A-fragments load straight from the
// padded g_xbf into registers (4 x b128 per visit, L2-hit, 2-deep prefetch).
// Only taps go through LDS (lane-variable shift table). Plain exclusive stores.
// Verified MFMA math (R2-R10), A-fragment bytes IDENTICAL to old xs[] path:
//   addr = rowbase + t0 + 256s + 16c + 8g (+16 for A2); padded rows make the
//   causal halo automatic (padded[t0+k] == old xs[k]).
//   b1 = kt[a][s1..+8), b2 = kt[a][s1+16..+24) with g<2 -> 0 (REQUIRED)
//   kt[a][((a+1)&7)+47-m] = tap[m];  a=c&7, s1=((a+1)&7)+15-c+8g (8-aligned)
//   D: col=c=lane&15, row=4g+qd -> t = 512w + 256s + 64g + 16qd + c
__global__ __launch_bounds__(256, 4) void lti_kernel(
    const float*    __restrict__ x,      // [N, T] fp32 (epilogue skip-connection)
    const int*      __restrict__ cnt,    // [N]
    const unsigned* __restrict__ slots,  // [N, CAP]
    float*          __restrict__ out)    // [N, T]
{
    const int n   = blockIdx.x;
    const int tid = threadIdx.x;
    const int w   = tid >> 6;        // t-quarter 0..3
    const int ln  = tid & 63;
    const int c   = ln & 15, g = ln >> 4;
    const int t0  = 512 * w;
    const int D   = 16 * c + 8 * g;  // fragment offset within the quarter

    __shared__ __align__(16) short kt_all[4][8][72];  // per-wave shifted taps table
    __shared__ unsigned bl[CAP];

    short (*kt)[72] = kt_all[w];

    short8 z8; z8[0]=0;z8[1]=0;z8[2]=0;z8[3]=0;z8[4]=0;z8[5]=0;z8[6]=0;z8[7]=0;

    {   // per-wave init: zero taps table (pads persist across experts)
        short8* kz = (short8*)&kt[0][0];   // 576 shorts = 72 short8
        kz[ln] = z8;
        if (ln < 8) kz[64 + ln] = z8;
    }
    if (tid < CAP) bl[tid] = slots[(size_t)n * CAP + tid];
    int L = cnt[n]; if (L > CAP) L = CAP;
    __syncthreads();

    f32x4 acc0 = {0,0,0,0}, acc1 = {0,0,0,0};
    short8  xa0A, xb0A, xa1A, xb1A, xa0B, xb0B, xa1B, xb1B;  // A-frags per stage
    short4v trA, trB;                                        // tap regs per stage

    const int a_ = c & 7;
    const int s1 = ((a_ + 1) & 7) + 15 - c + 8 * g;   // b128-aligned by construction

    // Load visit P's A-fragments + taps straight into registers (5 vmem, no LDS).
    #define LOADV(S, P)                                                                \
    {                                                                                  \
        const unsigned sv = bl[P];                                                     \
        const int e0 = __builtin_amdgcn_readfirstlane((int)(sv & 16383u));             \
        const int s0 = __builtin_amdgcn_readfirstlane((int)(sv >> 14));                \
        const short* rb = g_xbf + (size_t)s0 * RS + t0 + D;                            \
        xa0##S = *(const short8*)(rb);                                                 \
        xb0##S = *(const short8*)(rb + 16);                                            \
        xa1##S = *(const short8*)(rb + 256);                                           \
        xb1##S = *(const short8*)(rb + 272);                                           \
        tr##S  = *(const short4v*)(g_kbf + ((size_t)e0 << 5) + 4 * (ln & 7));          \
    }

    #define COMMIT(S)                                                                  \
    {                                                                                  \
        const int a2 = ln >> 3, pad = (a2 + 1) & 7, mb = 4 * (ln & 7);                 \
        kt[a2][pad + 47 - mb] = tr##S[0];                                              \
        kt[a2][pad + 46 - mb] = tr##S[1];                                              \
        kt[a2][pad + 45 - mb] = tr##S[2];                                              \
        kt[a2][pad + 44 - mb] = tr##S[3];                                              \
    }

    #define COMPUTE(S)                                                                 \
    {                                                                                  \
        const short8 b1 = *(const short8*)&kt[a_][s1];                                 \
        short8 b2 = *(const short8*)&kt[a_][s1 + 16];                                  \
        if (g < 2) b2 = z8;   /* k<16 zeroing is REQUIRED */                           \
        acc0 = __builtin_amdgcn_mfma_f32_16x16x32_bf16(xa0##S, b1, acc0, 0, 0, 0);     \
        acc0 = __builtin_amdgcn_mfma_f32_16x16x32_bf16(xb0##S, b2, acc0, 0, 0, 0);     \
        acc1 = __builtin_amdgcn_mfma_f32_16x16x32_bf16(xa1##S, b1, acc1, 0, 0, 0);     \
        acc1 = __builtin_amdgcn_mfma_f32_16x16x32_bf16(xb1##S, b2, acc1, 0, 0, 0);     \
    }

    if (L > 0) {
        LOADV(A, 0);
        if (L > 1) LOADV(B, 1);
        for (int i = 0; i < L; i += 2) {
            COMMIT(A);
            COMPUTE(A);
            if (i + 2 < L) LOADV(A, i + 2);
            if (i + 1 < L) { COMMIT(B); COMPUTE(B); }
            if (i + 3 < L) LOADV(B, i + 3);
        }
    }

    // Epilogue: wave owns out[n, t0..t0+512) exclusively -> plain stores (always
    // executed: full overwrite of poisoned d_out; acc==0 when L==0).
    const float* xr  = x   + (size_t)n * TT + t0;
    float*       orw = out + (size_t)n * TT + t0;
    #pragma unroll
    for (int qd = 0; qd < 4; ++qd) {
        const int ta = 64 * g + 16 * qd + c;
        orw[ta]       = xr[ta]       + acc0[qd];
        orw[256 + ta] = xr[256 + ta] + acc1[qd];
    }
    #undef LOADV
    #undef COMMIT
    #undef COMPUTE
}

extern "C" void kernel_launch(void* const* d_in, const int* in_sizes, int n_in,
                              void* d_out, int out_size, void* d_ws, size_t ws_size,
                              hipStream_t stream) {
    const float* x    = (const float*)d_in[0];
    const float* kern = (const float*)d_in[1];
    const int*   src  = (const int*)d_in[2];
    const int*   dst  = (const int*)d_in[3];
    float*       out  = (float*)d_out;

    int*      cnt   = (int*)d_ws;                       // 4 KB
    unsigned* slots = (unsigned*)((char*)d_ws + 4096);  // 256 KB

    cvt_kernel<<<dim3(NN + 1 + EE * KK / 8 / 256), dim3(256), 0, stream>>>(x, kern, cnt);
    csr_kernel<<<dim3(EE / 256), dim3(256), 0, stream>>>(src, dst, cnt, slots);
    lti_kernel<<<dim3(NN), dim3(256), 0, stream>>>(x, cnt, slots, out);
}

// Round 13
// 35.865 us; speedup vs baseline: 1.2674x; 1.0679x over previous
//
#include <hip/hip_runtime.h>
#include <hip/hip_bf16.h>

// Problem constants: B=1, N=1024, T=2048, E=16384, K=32.
#define TT  2048
#define KK  32
#define NN  1024
#define EE  16384
#define CAP 64     // per-row expert cap (Poisson(16); P(>64) ~ 1e-21)
#define RS  2080   // padded bf16 row stride: [32 causal zeros | 2048 row]

typedef short short8  __attribute__((ext_vector_type(8)));
typedef short short4v __attribute__((ext_vector_type(4)));
typedef float f32x4   __attribute__((ext_vector_type(4)));

// bf16 copies (device globals, rewritten every call).
// g_xbf rows are left-padded with 32 zeros -> halo/causality is branchless.
__device__ short g_xbf[NN * RS];   // 4.26 MB
__device__ short g_kbf[EE * KK];   // 1 MB

__device__ __forceinline__ short f2bf(float f) {
    __hip_bfloat16 h = __float2bfloat16(f);
    return __builtin_bit_cast(short, h);
}

// Prep A: blocks 0..1023: x row -> padded bf16 row; block 1024: zero cnt;
// blocks 1025..1280: kern -> bf16.
__global__ __launch_bounds__(256) void cvt_kernel(const float* __restrict__ x,
                                                  const float* __restrict__ kern,
                                                  int* __restrict__ cnt) {
    const int bid = blockIdx.x, tid = threadIdx.x;
    if (bid < NN) {
        const float4* xr = (const float4*)(x + (size_t)bid * TT);
        const float4 u = xr[2 * tid], v = xr[2 * tid + 1];
        short8 h;
        h[0]=f2bf(u.x); h[1]=f2bf(u.y); h[2]=f2bf(u.z); h[3]=f2bf(u.w);
        h[4]=f2bf(v.x); h[5]=f2bf(v.y); h[6]=f2bf(v.z); h[7]=f2bf(v.w);
        *(short8*)&g_xbf[(size_t)bid * RS + 32 + 8 * tid] = h;
        if (tid < 4) {
            short8 z; z[0]=0;z[1]=0;z[2]=0;z[3]=0;z[4]=0;z[5]=0;z[6]=0;z[7]=0;
            *(short8*)&g_xbf[(size_t)bid * RS + 8 * tid] = z;   // causal halo
        }
    } else if (bid == NN) {
        ((int4*)cnt)[tid] = make_int4(0, 0, 0, 0);              // 4 KB
    } else {
        const int i = (bid - NN - 1) * 256 + tid;               // 65536 thr, 8 ea
        const float4* k4 = (const float4*)kern;
        const float4 u = k4[2 * i], v = k4[2 * i + 1];
        short8 h;
        h[0]=f2bf(u.x); h[1]=f2bf(u.y); h[2]=f2bf(u.z); h[3]=f2bf(u.w);
        h[4]=f2bf(v.x); h[5]=f2bf(v.y); h[6]=f2bf(v.z); h[7]=f2bf(v.w);
        ((short8*)g_kbf)[i] = h;
    }
}

// Prep B: routing CSR. slots[d*CAP+p] packs (src<<14)|e.
__global__ __launch_bounds__(256) void csr_kernel(const int* __restrict__ src,
                                                  const int* __restrict__ dst,
                                                  int* __restrict__ cnt,
                                                  unsigned* __restrict__ slots) {
    const int e = blockIdx.x * 256 + threadIdx.x;   // 16384 threads
    const int d = dst[e];
    const int p = atomicAdd(&cnt[d], 1);
    if (p < CAP) slots[(size_t)d * CAP + p] = ((unsigned)src[e] << 14) | (unsigned)e;
}

// Main: grid 4096 = (row n, t-quarter) blocks of 128 thr = 2 parity waves.
// ~16 blocks/CU with dynamic refill -> straggler rows (L~Poisson(16), max~36)
// overlap fresh blocks instead of stalling their CU (R6-R12's half-occupancy
// signature). Parity wave p handles slots p, p+2, ...; partials combine via a
// 2 KB LDS buffer + one barrier; plain exclusive stores; no atomics.
// Per visit (unchanged from R12, verified): A-fragments straight from padded
// g_xbf into registers (4 x b128, shared scalar base), taps via LDS table.
//   A1 b128 at rowbase + t0 + 256s + 16c + 8g, A2 at +16 (bytes == old xs[])
//   b1 = kt[a][s1..+8), b2 = kt[a][s1+16..+24) with g<2 -> 0 (REQUIRED)
//   kt[a][((a+1)&7)+47-m] = tap[m];  a=c&7, s1=((a+1)&7)+15-c+8g (8-aligned)
//   D: col=c=lane&15, row=4g+qd -> t = 512w + 256s + 64g + 16qd + c
__global__ __launch_bounds__(128, 6) void lti_kernel(
    const float*    __restrict__ x,      // [N, T] fp32 (epilogue skip-connection)
    const int*      __restrict__ cnt,    // [N]
    const unsigned* __restrict__ slots,  // [N, CAP]
    float*          __restrict__ out)    // [N, T]
{
    const int bid = blockIdx.x;
    const int n   = bid >> 2;        // row
    const int w   = bid & 3;         // t-quarter
    const int tid = threadIdx.x;
    const int pw  = tid >> 6;        // parity wave 0..1
    const int ln  = tid & 63;
    const int c   = ln & 15, g = ln >> 4;
    const int t0  = 512 * w;
    const int D   = 16 * c + 8 * g;  // fragment offset within the quarter

    __shared__ __align__(16) short kt_all[2][8][72];  // per-wave shifted taps table
    __shared__ __align__(16) float red[512];          // parity-1 partials
    __shared__ unsigned bl[CAP];

    short (*kt)[72] = kt_all[pw];

    short8 z8; z8[0]=0;z8[1]=0;z8[2]=0;z8[3]=0;z8[4]=0;z8[5]=0;z8[6]=0;z8[7]=0;

    {   // per-wave init: zero own taps table (pads persist across experts)
        short8* kz = (short8*)&kt[0][0];   // 576 shorts = 72 short8
        kz[ln] = z8;
        if (ln < 8) kz[64 + ln] = z8;
    }
    if (tid < CAP) bl[tid] = slots[(size_t)n * CAP + tid];
    int L = cnt[n]; if (L > CAP) L = CAP;
    __syncthreads();

    const int M = (L - pw + 1) >> 1;         // this wave's visit count
    #define IDX(I) (pw + 2 * (I))

    f32x4 acc0 = {0,0,0,0}, acc1 = {0,0,0,0};
    short8  xa0A, xb0A, xa1A, xb1A, xa0B, xb0B, xa1B, xb1B;  // A-frags per stage
    short4v trA, trB;                                        // tap regs per stage

    const int a_ = c & 7;
    const int s1 = ((a_ + 1) & 7) + 15 - c + 8 * g;   // b128-aligned by construction

    // Load visit IDX(P)'s A-fragments + taps straight into registers (5 vmem).
    #define LOADV(S, P)                                                                \
    {                                                                                  \
        const unsigned sv = bl[P];                                                     \
        const int e0 = __builtin_amdgcn_readfirstlane((int)(sv & 16383u));             \
        const int s0 = __builtin_amdgcn_readfirstlane((int)(sv >> 14));                \
        const short* rb = g_xbf + (size_t)s0 * RS + t0 + D;                            \
        xa0##S = *(const short8*)(rb);                                                 \
        xb0##S = *(const short8*)(rb + 16);                                            \
        xa1##S = *(const short8*)(rb + 256);                                           \
        xb1##S = *(const short8*)(rb + 272);                                           \
        tr##S  = *(const short4v*)(g_kbf + ((size_t)e0 << 5) + 4 * (ln & 7));          \
    }

    #define COMMIT(S)                                                                  \
    {                                                                                  \
        const int a2 = ln >> 3, pad = (a2 + 1) & 7, mb = 4 * (ln & 7);                 \
        kt[a2][pad + 47 - mb] = tr##S[0];                                              \
        kt[a2][pad + 46 - mb] = tr##S[1];                                              \
        kt[a2][pad + 45 - mb] = tr##S[2];                                              \
        kt[a2][pad + 44 - mb] = tr##S[3];                                              \
    }

    #define COMPUTE(S)                                                                 \
    {                                                                                  \
        const short8 b1 = *(const short8*)&kt[a_][s1];                                 \
        short8 b2 = *(const short8*)&kt[a_][s1 + 16];                                  \
        if (g < 2) b2 = z8;   /* k<16 zeroing is REQUIRED */                           \
        acc0 = __builtin_amdgcn_mfma_f32_16x16x32_bf16(xa0##S, b1, acc0, 0, 0, 0);     \
        acc0 = __builtin_amdgcn_mfma_f32_16x16x32_bf16(xb0##S, b2, acc0, 0, 0, 0);     \
        acc1 = __builtin_amdgcn_mfma_f32_16x16x32_bf16(xa1##S, b1, acc1, 0, 0, 0);     \
        acc1 = __builtin_amdgcn_mfma_f32_16x16x32_bf16(xb1##S, b2, acc1, 0, 0, 0);     \
    }

    if (M > 0) {
        LOADV(A, IDX(0));
        if (M > 1) LOADV(B, IDX(1));
        for (int i = 0; i < M; i += 2) {
            COMMIT(A);
            COMPUTE(A);
            if (i + 2 < M) LOADV(A, IDX(i + 2));
            if (i + 1 < M) { COMMIT(B); COMPUTE(B); }
            if (i + 3 < M) LOADV(B, IDX(i + 3));
        }
    }

    // Parity combine (block-uniform control flow; acc==0 when M==0).
    if (pw == 1) {
        #pragma unroll
        for (int qd = 0; qd < 4; ++qd) {
            const int ta = 64 * g + 16 * qd + c;
            red[ta]       = acc0[qd];
            red[256 + ta] = acc1[qd];
        }
    }
    __syncthreads();
    if (pw == 0) {
        const float* xr  = x   + (size_t)n * TT + t0;
        float*       orw = out + (size_t)n * TT + t0;
        #pragma unroll
        for (int qd = 0; qd < 4; ++qd) {
            const int ta = 64 * g + 16 * qd + c;
            orw[ta]       = xr[ta]       + acc0[qd] + red[ta];
            orw[256 + ta] = xr[256 + ta] + acc1[qd] + red[256 + ta];
        }
    }
    #undef IDX
    #undef LOADV
    #undef COMMIT
    #undef COMPUTE
}

extern "C" void kernel_launch(void* const* d_in, const int* in_sizes, int n_in,
                              void* d_out, int out_size, void* d_ws, size_t ws_size,
                              hipStream_t stream) {
    const float* x    = (const float*)d_in[0];
    const float* kern = (const float*)d_in[1];
    const int*   src  = (const int*)d_in[2];
    const int*   dst  = (const int*)d_in[3];
    float*       out  = (float*)d_out;

    int*      cnt   = (int*)d_ws;                       // 4 KB
    unsigned* slots = (unsigned*)((char*)d_ws + 4096);  // 256 KB

    cvt_kernel<<<dim3(NN + 1 + EE * KK / 8 / 256), dim3(256), 0, stream>>>(x, kern, cnt);
    csr_kernel<<<dim3(EE / 256), dim3(256), 0, stream>>>(src, dst, cnt, slots);
    lti_kernel<<<dim3(NN * 4), dim3(128), 0, stream>>>(x, cnt, slots, out);
}